// Round 4
// baseline (331.167 us; speedup 1.0000x reference)
//
#include <hip/hip_runtime.h>

// ---------------------------------------------------------------------------
// GATBottleneck (ALL I/O fp32; compute bf16 MFMA, fp32 accum)
//
//  1. trcvt: x fp32 NCHW -> xt bf16 [16384][1024]
//  2. trcvt: WgT2 bf16 [4096][512]; WgT2[hj][c] = w_gat[c][hj]
//  3. cvt  : w_reduce, w_restore fp32 -> bf16 (already B^T layout)
//  4. gemm<1>: xr = relu(bn(xt @ w_reduce^T))          [16384][512] bf16
//  5. attproj: P[s][h][c] = sum_t w_gat[c][h*512+t]*att_s[h][t]   (fp32)
//  6. att    : a_s[n][h] = xr[n] . P[s][h]                        (fp32)
//  7. gemm<0>: Y = xr @ WgT2^T                         [16384][4096] bf16
//  8. agg2   : per node: head-softmax alphas over {self + 4 nbrs},
//              gat[n][j] = bias[j] + sum_e sum_h (alpha/8) Y[v_e][h*512+j]
//  9. gemm<3>: out = relu(bn(gat @ w_restore^T) + x)   -> fp32 NCHW
//
// GEMM: 128x128 tile, BK=32, 4 waves, mfma_f32_16x16x32_bf16,
//       global_load_lds width=16, fp32 accum, XCD-chunked block swizzle.
// MODE 0/1 use SWAPPED mfma operands (D transposed in regs) so each lane
// holds 4 consecutive output COLS -> u16x4 (8B) stores, 4x fewer store
// instructions and full-line write combining.  MODE 3 keeps original order
// (NCHW layout already gives 4 consecutive pixels per lane).
// edge_index is the fixed 4-neighbor grid + self loops -> analytic.
// ---------------------------------------------------------------------------

typedef unsigned short u16;
typedef __attribute__((ext_vector_type(4))) unsigned short u16x4;
typedef __attribute__((ext_vector_type(8))) unsigned short u16x8;
typedef __attribute__((ext_vector_type(8))) __bf16 bf16x8;
typedef __attribute__((ext_vector_type(4))) float f32x4;

#define B_    64
#define CIN   1024
#define CRED  512
#define COUT  1024
#define NPIX  256
#define HEADS 8
#define KGAT  4096
#define MTOT  16384
#define EPSB  1e-5f

__device__ __forceinline__ float b2f(u16 u) {
  union { unsigned u; float f; } c; c.u = ((unsigned)u) << 16; return c.f;
}
__device__ __forceinline__ u16 f2b(float f) {
  union { float f; unsigned u; } c; c.f = f;
  unsigned r = (c.u + 0x7FFFu + ((c.u >> 16) & 1u)) >> 16;
  return (u16)r;
}

__device__ __forceinline__ void gload_lds16(const void* g, void* lds) {
  __builtin_amdgcn_global_load_lds(
      (const __attribute__((address_space(1))) void*)g,
      (__attribute__((address_space(3))) void*)lds, 16, 0, 0);
}

// ------------- 64x64 transpose fp32 -> bf16 --------------------------------
__global__ __launch_bounds__(256) void trcvt_kernel(
    const float* __restrict__ src, u16* __restrict__ dst,
    int srs, int drs, long szs, long dzs)
{
  __shared__ float tile[64][65];
  const int t = threadIdx.x;
  const int tr = t >> 4, tc = (t & 15) * 4;
  const long sbase = (long)blockIdx.z * szs +
                     (long)(blockIdx.y * 64) * srs + blockIdx.x * 64;
#pragma unroll
  for (int i = 0; i < 4; ++i) {
    const int r = i * 16 + tr;
    const float4 v = *(const float4*)&src[sbase + (long)r * srs + tc];
    tile[r][tc]     = v.x;
    tile[r][tc + 1] = v.y;
    tile[r][tc + 2] = v.z;
    tile[r][tc + 3] = v.w;
  }
  __syncthreads();
  const long dbase = (long)blockIdx.z * dzs +
                     (long)(blockIdx.x * 64) * drs + blockIdx.y * 64;
#pragma unroll
  for (int i = 0; i < 4; ++i) {
    const int c = i * 16 + tr;  // dst-row = src-col
    u16x4 o;
#pragma unroll
    for (int q = 0; q < 4; ++q) o[q] = f2b(tile[tc + q][c]);
    *(u16x4*)&dst[dbase + (long)c * drs + tc] = o;
  }
}

// --------------------- elementwise fp32 -> bf16 convert --------------------
__global__ __launch_bounds__(256) void cvt_kernel(
    const float* __restrict__ src, u16* __restrict__ dst)
{
  const int i = (blockIdx.x * 256 + threadIdx.x) * 8;
  const float4 a = *(const float4*)&src[i];
  const float4 b = *(const float4*)&src[i + 4];
  u16x8 o;
  o[0] = f2b(a.x); o[1] = f2b(a.y); o[2] = f2b(a.z); o[3] = f2b(a.w);
  o[4] = f2b(b.x); o[5] = f2b(b.y); o[6] = f2b(b.z); o[7] = f2b(b.w);
  *(u16x8*)&dst[i] = o;
}

// ------------------------------ MFMA GEMM ----------------------------------
// C[m][n] = sum_k A[m][k]*Bt[n][k]   (A [M][K] bf16, Bt [N][K] bf16)
// MODE 0: out16 = C                   bf16 row-major   (swapped operands)
// MODE 1: out16 = relu(bn(C))         bf16 row-major   (swapped operands)
// MODE 3: out32 = relu(bn(C) + auxf)  fp32 NCHW        (original order)
#define BM 128
#define BN 128
#define BK 32

template <int MODE>
__global__ __launch_bounds__(256, 2) void gemm_kernel(
    const u16* __restrict__ A, const u16* __restrict__ Bt,
    u16* __restrict__ out16, float* __restrict__ out32,
    const float* __restrict__ pg, const float* __restrict__ pb,
    const float* __restrict__ pm, const float* __restrict__ pv,
    const float* __restrict__ auxf, int K, int Nloc)
{
  constexpr bool SW = (MODE != 3);  // swapped-operand (col-major regs) mode

  // XCD-chunked block swizzle (nwg % 8 == 0 for all our grids)
  const int gx = gridDim.x;
  const int nwg = gx * gridDim.y;
  int lin = blockIdx.y * gx + blockIdx.x;
  lin = (lin & 7) * (nwg >> 3) + (lin >> 3);
  const int m0 = (lin / gx) * BM, n0 = (lin % gx) * BN;

  __shared__ u16 As[BM * BK];
  __shared__ u16 Bs[BN * BK];
  const int tid = threadIdx.x;
  const int wave = tid >> 6, lane = tid & 63;

  // staging: flat elem = issue*2048 + wave*512 + lane*8 ; row = e/32, k = e%32
  const int eA0 = wave * 512 + lane * 8;
  const int eA1 = eA0 + 2048;
  const u16* gA0 = A + (size_t)(m0 + (eA0 >> 5)) * K + (eA0 & 31);
  const u16* gA1 = A + (size_t)(m0 + (eA1 >> 5)) * K + (eA1 & 31);
  const u16* gB0 = Bt + (size_t)(n0 + (eA0 >> 5)) * K + (eA0 & 31);
  const u16* gB1 = Bt + (size_t)(n0 + (eA1 >> 5)) * K + (eA1 & 31);
  u16* lA0 = &As[wave * 512];
  u16* lA1 = &As[wave * 512 + 2048];
  u16* lB0 = &Bs[wave * 512];
  u16* lB1 = &Bs[wave * 512 + 2048];

  f32x4 acc[4][4];
#pragma unroll
  for (int i = 0; i < 4; ++i)
#pragma unroll
    for (int j = 0; j < 4; ++j) acc[i][j] = f32x4{0.f, 0.f, 0.f, 0.f};

  const int wr = wave >> 1, wc = wave & 1;
  const int l15 = lane & 15, kb = (lane >> 4) * 8;

  for (int kt = 0; kt < K; kt += BK) {
    gload_lds16(gA0, lA0); gload_lds16(gA1, lA1);
    gload_lds16(gB0, lB0); gload_lds16(gB1, lB1);
    gA0 += BK; gA1 += BK; gB0 += BK; gB1 += BK;
    __syncthreads();
    bf16x8 af[4], bfr[4];
#pragma unroll
    for (int f = 0; f < 4; ++f) {
      af[f]  = *(const bf16x8*)&As[(wr * 64 + f * 16 + l15) * BK + kb];
      bfr[f] = *(const bf16x8*)&Bs[(wc * 64 + f * 16 + l15) * BK + kb];
    }
#pragma unroll
    for (int fm = 0; fm < 4; ++fm)
#pragma unroll
      for (int fn = 0; fn < 4; ++fn)
        acc[fm][fn] = SW
            ? __builtin_amdgcn_mfma_f32_16x16x32_bf16(
                  bfr[fn], af[fm], acc[fm][fn], 0, 0, 0)
            : __builtin_amdgcn_mfma_f32_16x16x32_bf16(
                  af[fm], bfr[fn], acc[fm][fn], 0, 0, 0);
    __syncthreads();
  }

  if (SW) {
    // D transposed: acc[fm][fn] reg r <-> row = m0+wr*64+fm*16+l15,
    //                                   col = n0+wc*64+fn*16+(lane>>4)*4+r
    const int rowb = m0 + wr * 64 + l15;
    const int colq = (lane >> 4) * 4;
#pragma unroll
    for (int fn = 0; fn < 4; ++fn) {
      const int colb = n0 + wc * 64 + fn * 16 + colq;
      float4 sc4, of4;
      if (MODE == 1) {
        const float4 g = *(const float4*)&pg[colb];
        const float4 b = *(const float4*)&pb[colb];
        const float4 m = *(const float4*)&pm[colb];
        const float4 v = *(const float4*)&pv[colb];
        sc4.x = g.x * rsqrtf(v.x + EPSB); of4.x = b.x - m.x * sc4.x;
        sc4.y = g.y * rsqrtf(v.y + EPSB); of4.y = b.y - m.y * sc4.y;
        sc4.z = g.z * rsqrtf(v.z + EPSB); of4.z = b.z - m.z * sc4.z;
        sc4.w = g.w * rsqrtf(v.w + EPSB); of4.w = b.w - m.w * sc4.w;
      }
#pragma unroll
      for (int fm = 0; fm < 4; ++fm) {
        const int row = rowb + fm * 16;
        u16x4 ov;
        if (MODE == 1) {
          ov[0] = f2b(fmaxf(acc[fm][fn][0] * sc4.x + of4.x, 0.f));
          ov[1] = f2b(fmaxf(acc[fm][fn][1] * sc4.y + of4.y, 0.f));
          ov[2] = f2b(fmaxf(acc[fm][fn][2] * sc4.z + of4.z, 0.f));
          ov[3] = f2b(fmaxf(acc[fm][fn][3] * sc4.w + of4.w, 0.f));
        } else {
#pragma unroll
          for (int r = 0; r < 4; ++r) ov[r] = f2b(acc[fm][fn][r]);
        }
        *(u16x4*)&out16[(size_t)row * Nloc + colb] = ov;
      }
    }
  } else {
    // original order: reg r <-> row = rowb+fm*16+r (pixel), col via l15 (chan)
    const int rowb = m0 + wr * 64 + (lane >> 4) * 4;
#pragma unroll
    for (int fn = 0; fn < 4; ++fn) {
      const int col = n0 + wc * 64 + fn * 16 + l15;
      const float sc = pg[col] * rsqrtf(pv[col] + EPSB);
      const float off = pb[col] - pm[col] * sc;
#pragma unroll
      for (int fm = 0; fm < 4; ++fm) {
        const int row = rowb + fm * 16;
        const int bimg = row >> 8, p0 = row & 255;
        const size_t oa = (size_t)bimg * (COUT * NPIX) + (size_t)col * NPIX + p0;
        const float4 rv = *(const float4*)&auxf[oa];
        float4 ov;
        ov.x = fmaxf(acc[fm][fn][0] * sc + off + rv.x, 0.f);
        ov.y = fmaxf(acc[fm][fn][1] * sc + off + rv.y, 0.f);
        ov.z = fmaxf(acc[fm][fn][2] * sc + off + rv.z, 0.f);
        ov.w = fmaxf(acc[fm][fn][3] * sc + off + rv.w, 0.f);
        *(float4*)&out32[oa] = ov;
      }
    }
  }
}

// ---------- P[s][h][c] = sum_t w_gat[c][h*512+t] * att_s[h][t] (fp32) ------
__global__ __launch_bounds__(256) void attproj_kernel(
    const float* __restrict__ w_gat, const float* __restrict__ att_src,
    const float* __restrict__ att_dst, float* __restrict__ P)
{
  __shared__ float av[CRED];
  const int sh = blockIdx.x;  // 0..15 : s = sh>>3, h = sh&7
  const int s = sh >> 3, h = sh & 7;
  const float* att = (s == 0) ? att_src : att_dst;
  for (int t = threadIdx.x; t < CRED; t += 256) av[t] = att[h * CRED + t];
  __syncthreads();
#pragma unroll
  for (int half = 0; half < 2; ++half) {
    const int c = threadIdx.x + half * 256;
    const float* wrow = w_gat + (size_t)c * KGAT + h * CRED;
    float acc = 0.f;
    for (int j = 0; j < CRED; j += 4) {
      const float4 w = *(const float4*)&wrow[j];
      acc += w.x * av[j] + w.y * av[j + 1] + w.z * av[j + 2] + w.w * av[j + 3];
    }
    P[(size_t)sh * CRED + c] = acc;
  }
}

// ---------- a_all[s][n][h] = xr[n] . P[s][h]   (one wave per node) ---------
__global__ __launch_bounds__(256) void att_kernel(
    const u16* __restrict__ xr, const float* __restrict__ P,
    float* __restrict__ a_all)
{
  const int wave = threadIdx.x >> 6, lane = threadIdx.x & 63;
  const int m = blockIdx.x * 4 + wave;
  const int sh = lane & 15, q = lane >> 4;
  const u16* xp = xr + (size_t)m * CRED + q * 128;
  const float* Pp = P + (size_t)sh * CRED + q * 128;
  float s = 0.f;
#pragma unroll
  for (int c = 0; c < 128; c += 8) {
    u16x8 xv = *(const u16x8*)&xp[c];
#pragma unroll
    for (int t = 0; t < 8; ++t) s += b2f(xv[t]) * Pp[c + t];
  }
  s += __shfl_xor(s, 16);
  s += __shfl_xor(s, 32);
  if (q == 0)
    a_all[(size_t)(sh >> 3) * MTOT * HEADS + (size_t)m * HEADS + (sh & 7)] = s;
}

// ---- per node: softmax alphas (8 heads x 5 edges) in LDS, then
//      gat[n][j] = bias[j] + sum_e sum_h (alpha[e][h]/8) * Y[v_e][h*512+j] ---
__global__ __launch_bounds__(256) void agg2_kernel(
    const u16* __restrict__ Y, const float* __restrict__ a_all,
    const float* __restrict__ gat_bias, u16* __restrict__ gat)
{
  // XCD-chunked swizzle: consecutive nodes on one XCD -> neighbor-row L2 reuse
  int bid = blockIdx.x;
  bid = (bid & 7) * (MTOT >> 3) + (bid >> 3);
  const int u = bid & 255, b = bid >> 8;
  const int gi = u >> 4, gj = u & 15;
  const size_t nb = (size_t)b * NPIX;
  const int t = threadIdx.x;

  const int v0 = u;
  const int v1 = (gi > 0)  ? u - 16 : -1;
  const int v2 = (gi < 15) ? u + 16 : -1;
  const int v3 = (gj > 0)  ? u - 1  : -1;
  const int v4 = (gj < 15) ? u + 1  : -1;
  const int vs[5] = { v0, v1, v2, v3, v4 };

  __shared__ float alf[5][8];
  if (t < 8) {
    const int h = t;
    const float* a_src = a_all;
    const float* a_dst = a_all + (size_t)MTOT * HEADS;
    const float adst = a_dst[(nb + u) * HEADS + h];
    float l[5];
    float mx = -1e30f;
#pragma unroll
    for (int e = 0; e < 5; ++e) {
      if (vs[e] >= 0) {
        const float xx = a_src[(nb + vs[e]) * HEADS + h] + adst;
        l[e] = xx > 0.f ? xx : 0.2f * xx;  // leaky_relu(0.2)
        mx = fmaxf(mx, l[e]);
      } else {
        l[e] = -1e30f;
      }
    }
    float s = 0.f, ee[5];
#pragma unroll
    for (int e = 0; e < 5; ++e) {
      ee[e] = (vs[e] >= 0) ? __expf(l[e] - mx) : 0.f;
      s += ee[e];
    }
    const float inv = 0.125f / s;  // head-mean folded
#pragma unroll
    for (int e = 0; e < 5; ++e) alf[e][h] = ee[e] * inv;
  }
  __syncthreads();

  const int j0 = t * 2;
  float o0 = gat_bias[j0], o1 = gat_bias[j0 + 1];
#pragma unroll
  for (int e = 0; e < 5; ++e) {
    const int vv = vs[e];
    if (vv < 0) continue;
    const u16* yp = Y + (nb + vv) * (size_t)KGAT + j0;
#pragma unroll
    for (int h = 0; h < HEADS; ++h) {
      const float a = alf[e][h];
      const unsigned w = *(const unsigned*)(yp + h * CRED);
      o0 += a * b2f((u16)(w & 0xffffu));
      o1 += a * b2f((u16)(w >> 16));
    }
  }
  const unsigned ow = ((unsigned)f2b(o1) << 16) | (unsigned)f2b(o0);
  *(unsigned*)&gat[(nb + u) * (size_t)CRED + j0] = ow;
}

// ---------------------------------------------------------------------------
extern "C" void kernel_launch(void* const* d_in, const int* in_sizes, int n_in,
                              void* d_out, int out_size, void* d_ws, size_t ws_size,
                              hipStream_t stream)
{
  const float* x         = (const float*)d_in[0];
  const float* w_reduce  = (const float*)d_in[1];
  const float* g_red     = (const float*)d_in[2];
  const float* b_red     = (const float*)d_in[3];
  const float* m_red     = (const float*)d_in[4];
  const float* v_red     = (const float*)d_in[5];
  const float* w_gat     = (const float*)d_in[6];
  const float* att_src   = (const float*)d_in[7];
  const float* att_dst   = (const float*)d_in[8];
  const float* gat_bias  = (const float*)d_in[9];
  const float* w_restore = (const float*)d_in[10];
  const float* g_res     = (const float*)d_in[11];
  const float* b_res     = (const float*)d_in[12];
  const float* m_res     = (const float*)d_in[13];
  const float* v_res     = (const float*)d_in[14];
  // d_in[15] = edge_index (fixed 4-neighbor grid + self loops): analytic.

  // ---- workspace layout (xt aliases Y: xt dead before Y is written) ----
  constexpr size_t SZ_Y    = (size_t)MTOT * KGAT * 2;  // 134,217,728
  constexpr size_t SZ_XR   = (size_t)MTOT * CRED * 2;  //  16,777,216
  constexpr size_t SZ_GAT  = SZ_XR;                    //  16,777,216
  constexpr size_t SZ_WGT  = (size_t)KGAT * CRED * 2;  //   4,194,304
  constexpr size_t SZ_WRD  = (size_t)CRED * CIN * 2;   //   1,048,576
  constexpr size_t SZ_WRS  = (size_t)COUT * CRED * 2;  //   1,048,576
  constexpr size_t SZ_P    = (size_t)16 * CRED * 4;    //      32,768
  char* ws = (char*)d_ws;
  u16*   Y      = (u16*)ws;
  u16*   xt     = (u16*)ws;  // alias of Y
  u16*   xr     = (u16*)(ws + SZ_Y);
  u16*   gat    = (u16*)(ws + SZ_Y + SZ_XR);
  u16*   WgT2   = (u16*)(ws + SZ_Y + SZ_XR + SZ_GAT);
  u16*   wred_b = (u16*)(ws + SZ_Y + SZ_XR + SZ_GAT + SZ_WGT);
  u16*   wres_b = (u16*)(ws + SZ_Y + SZ_XR + SZ_GAT + SZ_WGT + SZ_WRD);
  float* P      = (float*)(ws + SZ_Y + SZ_XR + SZ_GAT + SZ_WGT + SZ_WRD + SZ_WRS);
  float* a_all  = (float*)(ws + SZ_Y + SZ_XR + SZ_GAT + SZ_WGT + SZ_WRD + SZ_WRS + SZ_P);
  float* outp   = (float*)d_out;

  // 1) xt[(b*256+p)][ch] = bf16(x[b][ch][p])
  trcvt_kernel<<<dim3(4, 16, 64), 256, 0, stream>>>(
      x, xt, NPIX, CIN, (long)CIN * NPIX, (long)CIN * NPIX);
  // 2) WgT2[hj][c] = bf16(w_gat[c][hj])   ([4096][512])
  trcvt_kernel<<<dim3(64, 8, 1), 256, 0, stream>>>(
      w_gat, WgT2, KGAT, CRED, 0, 0);
  // 3) weight converts (layouts already B^T for their GEMMs)
  cvt_kernel<<<(CRED * CIN) / 2048, 256, 0, stream>>>(w_reduce, wred_b);
  cvt_kernel<<<(COUT * CRED) / 2048, 256, 0, stream>>>(w_restore, wres_b);
  // 4) xr = relu(bn(xt @ w_reduce^T))
  gemm_kernel<1><<<dim3(4, 128), 256, 0, stream>>>(
      xt, wred_b, xr, nullptr, g_red, b_red, m_red, v_red, nullptr, CIN, CRED);
  // 5) attention projections P  (fp32 weights)
  attproj_kernel<<<16, 256, 0, stream>>>(w_gat, att_src, att_dst, P);
  // 6) a_src / a_dst
  att_kernel<<<MTOT / 4, 256, 0, stream>>>(xr, P, a_all);
  // 7) Y = xr @ WgT2^T  (per-head projected features, M=16384 N=4096 K=512)
  gemm_kernel<0><<<dim3(32, 128), 256, 0, stream>>>(
      xr, WgT2, Y, nullptr, nullptr, nullptr, nullptr, nullptr, nullptr,
      CRED, KGAT);
  // 8) gat = head-mean of alpha-aggregated Y + gat_bias
  agg2_kernel<<<MTOT, 256, 0, stream>>>(Y, a_all, gat_bias, gat);
  // 9) out = relu(bn(gat @ w_restore^T) + x) -> fp32 NCHW
  gemm_kernel<3><<<dim3(8, 128), 256, 0, stream>>>(
      gat, wres_b, nullptr, outp, g_res, b_res, m_res, v_res, x, CRED, COUT);
  (void)in_sizes; (void)n_in; (void)out_size; (void)ws_size;
}

// Round 5
// 317.961 us; speedup vs baseline: 1.0415x; 1.0415x over previous
//
#include <hip/hip_runtime.h>

// ---------------------------------------------------------------------------
// GATBottleneck (ALL I/O fp32; compute bf16 MFMA, fp32 accum)
//
//  1. trcvt: x fp32 NCHW -> xt bf16 [16384][1024]
//  2. trcvt: WgT2 bf16 [4096][512]; WgT2[hj][c] = w_gat[c][hj]
//  3. cvt  : w_reduce, w_restore fp32 -> bf16 (already B^T layout)
//  4. gemm<1>: xr = relu(bn(xt @ w_reduce^T))          [16384][512] bf16
//  5. attproj: P[s][h][c] = sum_t w_gat[c][h*512+t]*att_s[h][t]   (fp32)
//  6. att    : a_s[n][h] = xr[n] . P[s][h]                        (fp32)
//  7. gemm8p : Y = xr @ WgT2^T   [16384][4096] bf16  -- 256x256 tile, BK=32,
//              8 waves, 4-deep LDS pipeline, counted vmcnt(4), swizzled LDS,
//              setprio around MFMA clusters (T1+T2+T3+T4+T5)
//  8. agg2   : per node: head-softmax alphas over {self + 4 nbrs},
//              gat[n][j] = bias[j] + sum_e sum_h (alpha/8) Y[v_e][h*512+j]
//  9. gemm<3>: out = relu(bn(gat @ w_restore^T) + x)   -> fp32 NCHW
// edge_index is the fixed 4-neighbor grid + self loops -> analytic.
// ---------------------------------------------------------------------------

typedef unsigned short u16;
typedef __attribute__((ext_vector_type(4))) unsigned short u16x4;
typedef __attribute__((ext_vector_type(8))) unsigned short u16x8;
typedef __attribute__((ext_vector_type(8))) __bf16 bf16x8;
typedef __attribute__((ext_vector_type(4))) float f32x4;

#define B_    64
#define CIN   1024
#define CRED  512
#define COUT  1024
#define NPIX  256
#define HEADS 8
#define KGAT  4096
#define MTOT  16384
#define EPSB  1e-5f

__device__ __forceinline__ float b2f(u16 u) {
  union { unsigned u; float f; } c; c.u = ((unsigned)u) << 16; return c.f;
}
__device__ __forceinline__ u16 f2b(float f) {
  union { float f; unsigned u; } c; c.f = f;
  unsigned r = (c.u + 0x7FFFu + ((c.u >> 16) & 1u)) >> 16;
  return (u16)r;
}

__device__ __forceinline__ void gload_lds16(const void* g, void* lds) {
  __builtin_amdgcn_global_load_lds(
      (const __attribute__((address_space(1))) void*)g,
      (__attribute__((address_space(3))) void*)lds, 16, 0, 0);
}

// ================= 256x256 pipelined GEMM: Y = A @ Bt^T ====================
// A [16384][512] bf16, Bt [4096][512] bf16, out [16384][4096] bf16.
// 8 waves (2 M x 4 N), wave tile 128x64.  BK=32, 16 K-tiles.
// LDS: 4 buffers x { A: 256x32 (16KB) | B: 256x32 (16KB) } = 128 KiB.
// Swizzle: element (row,k) stored at k-block (k/8) ^ (row&3)  (16B units);
//   staging pre-swizzles the GLOBAL source so LDS dest stays linear (m173),
//   ds_read applies the same XOR -> conflict-free b128 reads both sides.
// Pipeline: while computing T (buf T&3), stage T+2 (buf (T+2)&3).
//   Entering tile T: vmcnt(4) allows {A(T+1),B(T+1)} in flight, guarantees
//   T resident; raw s_barrier (NO count drain).  vmcnt(0) only at T=15.
__global__ __launch_bounds__(512, 1) void gemm8p_kernel(
    const u16* __restrict__ A, const u16* __restrict__ Bt,
    u16* __restrict__ out)
{
  extern __shared__ u16 lds[];
  const int tid = threadIdx.x;
  const int wave = tid >> 6, lane = tid & 63;
  const int wm = wave >> 2, wn = wave & 3;
  const int l15 = lane & 15, l4 = lane >> 4;

  // XCD-chunked swizzle over 1024 blocks (16 n-blocks x 64 m-blocks)
  int lin = blockIdx.y * 16 + blockIdx.x;
  lin = (lin & 7) * 128 + (lin >> 3);
  const int m0 = (lin >> 4) * 256;
  const int n0 = (lin & 15) * 256;

  // staging maps: 16B slot f = issue*512 + tid -> (row = f>>2, kblk' = f&3),
  // fetches global kblk = kblk' ^ (row&3)  (inverse == same involution)
  int offS[2], ldsS[2];
#pragma unroll
  for (int i = 0; i < 2; ++i) {
    const int f = i * 512 + tid;
    const int r = f >> 2;
    const int kb = (f & 3) ^ (r & 3);
    offS[i] = r * 512 + kb * 8;          // element offset: row*K + k
    ldsS[i] = (i * 512 + wave * 64) * 8; // wave-uniform base + lane*8 u16
  }
  const u16* gA = A + (size_t)m0 * 512;
  const u16* gB = Bt + (size_t)n0 * 512;

  auto stageA = [&](int kt) {
    const int bo = (kt & 3) * 16384;
    gload_lds16(gA + kt * 32 + offS[0], &lds[bo + ldsS[0]]);
    gload_lds16(gA + kt * 32 + offS[1], &lds[bo + ldsS[1]]);
  };
  auto stageB = [&](int kt) {
    const int bo = (kt & 3) * 16384 + 8192;
    gload_lds16(gB + kt * 32 + offS[0], &lds[bo + ldsS[0]]);
    gload_lds16(gB + kt * 32 + offS[1], &lds[bo + ldsS[1]]);
  };

  f32x4 acc[8][4];
#pragma unroll
  for (int i = 0; i < 8; ++i)
#pragma unroll
    for (int j = 0; j < 4; ++j) acc[i][j] = f32x4{0.f, 0.f, 0.f, 0.f};

  // ds_read bases: frag (row = base + fm*16 + l15, kblk = l4), swizzled.
  // (row&3) == (l15&3) since fm*16, wm*128, wn*64 are multiples of 4.
  const int kq = (l4 ^ (l15 & 3)) * 8;
  const int aBase = (wm * 128 + l15) * 32 + kq;
  const int bBase = 8192 + (wn * 64 + l15) * 32 + kq;

  stageA(0); stageB(0); stageA(1); stageB(1);

  for (int kt = 0; kt < 16; ++kt) {
    if (kt == 15) { asm volatile("s_waitcnt vmcnt(0)" ::: "memory"); }
    else         { asm volatile("s_waitcnt vmcnt(4)" ::: "memory"); }
    __builtin_amdgcn_s_barrier();
    asm volatile("" ::: "memory");
    const int bo = (kt & 3) * 16384;
    bf16x8 bfr[4], af[4];
#pragma unroll
    for (int f = 0; f < 4; ++f)
      bfr[f] = *(const bf16x8*)&lds[bo + bBase + f * 512];
#pragma unroll
    for (int f = 0; f < 4; ++f)
      af[f] = *(const bf16x8*)&lds[bo + aBase + f * 512];
    if (kt < 14) stageA(kt + 2);
    __builtin_amdgcn_s_setprio(1);
#pragma unroll
    for (int fm = 0; fm < 4; ++fm)
#pragma unroll
      for (int fn = 0; fn < 4; ++fn)
        acc[fm][fn] = __builtin_amdgcn_mfma_f32_16x16x32_bf16(
            af[fm], bfr[fn], acc[fm][fn], 0, 0, 0);
    __builtin_amdgcn_s_setprio(0);
    __builtin_amdgcn_s_barrier();
    // phase B: rows 64..127 of the wave tile (fm 4..7), reuse bfr
#pragma unroll
    for (int f = 0; f < 4; ++f)
      af[f] = *(const bf16x8*)&lds[bo + aBase + (f + 4) * 512];
    if (kt < 14) stageB(kt + 2);
    __builtin_amdgcn_s_setprio(1);
#pragma unroll
    for (int fm = 0; fm < 4; ++fm)
#pragma unroll
      for (int fn = 0; fn < 4; ++fn)
        acc[fm + 4][fn] = __builtin_amdgcn_mfma_f32_16x16x32_bf16(
            af[fm], bfr[fn], acc[fm + 4][fn], 0, 0, 0);
    __builtin_amdgcn_s_setprio(0);
  }

  // epilogue: row = m0 + wm*128 + fm*16 + l4*4 + r; col = n0 + wn*64 + fn*16 + l15
  const int rowb = m0 + wm * 128 + l4 * 4;
  const int colb = n0 + wn * 64 + l15;
#pragma unroll
  for (int fm = 0; fm < 8; ++fm)
#pragma unroll
    for (int fn = 0; fn < 4; ++fn)
#pragma unroll
      for (int r = 0; r < 4; ++r)
        out[(size_t)(rowb + fm * 16 + r) * KGAT + colb + fn * 16] =
            f2b(acc[fm][fn][r]);
}

// ------------- 64x64 transpose fp32 -> bf16 --------------------------------
__global__ __launch_bounds__(256) void trcvt_kernel(
    const float* __restrict__ src, u16* __restrict__ dst,
    int srs, int drs, long szs, long dzs)
{
  __shared__ float tile[64][65];
  const int t = threadIdx.x;
  const int tr = t >> 4, tc = (t & 15) * 4;
  const long sbase = (long)blockIdx.z * szs +
                     (long)(blockIdx.y * 64) * srs + blockIdx.x * 64;
#pragma unroll
  for (int i = 0; i < 4; ++i) {
    const int r = i * 16 + tr;
    const float4 v = *(const float4*)&src[sbase + (long)r * srs + tc];
    tile[r][tc]     = v.x;
    tile[r][tc + 1] = v.y;
    tile[r][tc + 2] = v.z;
    tile[r][tc + 3] = v.w;
  }
  __syncthreads();
  const long dbase = (long)blockIdx.z * dzs +
                     (long)(blockIdx.x * 64) * drs + blockIdx.y * 64;
#pragma unroll
  for (int i = 0; i < 4; ++i) {
    const int c = i * 16 + tr;
    u16x4 o;
#pragma unroll
    for (int q = 0; q < 4; ++q) o[q] = f2b(tile[tc + q][c]);
    *(u16x4*)&dst[dbase + (long)c * drs + tc] = o;
  }
}

// --------------------- elementwise fp32 -> bf16 convert --------------------
__global__ __launch_bounds__(256) void cvt_kernel(
    const float* __restrict__ src, u16* __restrict__ dst)
{
  const int i = (blockIdx.x * 256 + threadIdx.x) * 8;
  const float4 a = *(const float4*)&src[i];
  const float4 b = *(const float4*)&src[i + 4];
  u16x8 o;
  o[0] = f2b(a.x); o[1] = f2b(a.y); o[2] = f2b(a.z); o[3] = f2b(a.w);
  o[4] = f2b(b.x); o[5] = f2b(b.y); o[6] = f2b(b.z); o[7] = f2b(b.w);
  *(u16x8*)&dst[i] = o;
}

// ------------------------- 128x128 MFMA GEMM -------------------------------
// MODE 1: out16 = relu(bn(C)) bf16 row-major   (pg..pv fp32, len Nloc)
// MODE 3: out32 = relu(bn(C) + auxf) fp32 NCHW (auxf = x residual)
#define BM 128
#define BN 128
#define BK 32

template <int MODE>
__global__ __launch_bounds__(256, 2) void gemm_kernel(
    const u16* __restrict__ A, const u16* __restrict__ Bt,
    u16* __restrict__ out16, float* __restrict__ out32,
    const float* __restrict__ pg, const float* __restrict__ pb,
    const float* __restrict__ pm, const float* __restrict__ pv,
    const float* __restrict__ auxf, int K, int Nloc)
{
  const int gx = gridDim.x;
  const int nwg = gx * gridDim.y;
  int lin = blockIdx.y * gx + blockIdx.x;
  lin = (lin & 7) * (nwg >> 3) + (lin >> 3);
  const int m0 = (lin / gx) * BM, n0 = (lin % gx) * BN;

  __shared__ u16 As[BM * BK];
  __shared__ u16 Bs[BN * BK];
  const int tid = threadIdx.x;
  const int wave = tid >> 6, lane = tid & 63;

  const int eA0 = wave * 512 + lane * 8;
  const int eA1 = eA0 + 2048;
  const u16* gA0 = A + (size_t)(m0 + (eA0 >> 5)) * K + (eA0 & 31);
  const u16* gA1 = A + (size_t)(m0 + (eA1 >> 5)) * K + (eA1 & 31);
  const u16* gB0 = Bt + (size_t)(n0 + (eA0 >> 5)) * K + (eA0 & 31);
  const u16* gB1 = Bt + (size_t)(n0 + (eA1 >> 5)) * K + (eA1 & 31);
  u16* lA0 = &As[wave * 512];
  u16* lA1 = &As[wave * 512 + 2048];
  u16* lB0 = &Bs[wave * 512];
  u16* lB1 = &Bs[wave * 512 + 2048];

  f32x4 acc[4][4];
#pragma unroll
  for (int i = 0; i < 4; ++i)
#pragma unroll
    for (int j = 0; j < 4; ++j) acc[i][j] = f32x4{0.f, 0.f, 0.f, 0.f};

  const int wr = wave >> 1, wc = wave & 1;
  const int l15 = lane & 15, kb = (lane >> 4) * 8;

  for (int kt = 0; kt < K; kt += BK) {
    gload_lds16(gA0, lA0); gload_lds16(gA1, lA1);
    gload_lds16(gB0, lB0); gload_lds16(gB1, lB1);
    gA0 += BK; gA1 += BK; gB0 += BK; gB1 += BK;
    __syncthreads();
    bf16x8 af[4], bfr[4];
#pragma unroll
    for (int f = 0; f < 4; ++f) {
      af[f]  = *(const bf16x8*)&As[(wr * 64 + f * 16 + l15) * BK + kb];
      bfr[f] = *(const bf16x8*)&Bs[(wc * 64 + f * 16 + l15) * BK + kb];
    }
#pragma unroll
    for (int fm = 0; fm < 4; ++fm)
#pragma unroll
      for (int fn = 0; fn < 4; ++fn)
        acc[fm][fn] = __builtin_amdgcn_mfma_f32_16x16x32_bf16(
            af[fm], bfr[fn], acc[fm][fn], 0, 0, 0);
    __syncthreads();
  }

  const int rowb = m0 + wr * 64 + (lane >> 4) * 4;
#pragma unroll
  for (int fn = 0; fn < 4; ++fn) {
    const int col = n0 + wc * 64 + fn * 16 + l15;
    const float sc = pg[col] * rsqrtf(pv[col] + EPSB);
    const float off = pb[col] - pm[col] * sc;
#pragma unroll
    for (int fm = 0; fm < 4; ++fm) {
      const int row = rowb + fm * 16;
      if (MODE == 3) {
        const int bimg = row >> 8, p0 = row & 255;
        const size_t oa = (size_t)bimg * (COUT * NPIX) + (size_t)col * NPIX + p0;
        const float4 rv = *(const float4*)&auxf[oa];
        float4 ov;
        ov.x = fmaxf(acc[fm][fn][0] * sc + off + rv.x, 0.f);
        ov.y = fmaxf(acc[fm][fn][1] * sc + off + rv.y, 0.f);
        ov.z = fmaxf(acc[fm][fn][2] * sc + off + rv.z, 0.f);
        ov.w = fmaxf(acc[fm][fn][3] * sc + off + rv.w, 0.f);
        *(float4*)&out32[oa] = ov;
      } else {
#pragma unroll
        for (int r = 0; r < 4; ++r) {
          const float y = fmaxf(acc[fm][fn][r] * sc + off, 0.f);
          out16[(size_t)(row + r) * Nloc + col] = f2b(y);
        }
      }
    }
  }
}

// ---------- P[s][h][c] = sum_t w_gat[c][h*512+t] * att_s[h][t] (fp32) ------
__global__ __launch_bounds__(256) void attproj_kernel(
    const float* __restrict__ w_gat, const float* __restrict__ att_src,
    const float* __restrict__ att_dst, float* __restrict__ P)
{
  __shared__ float av[CRED];
  const int sh = blockIdx.x;
  const int s = sh >> 3, h = sh & 7;
  const float* att = (s == 0) ? att_src : att_dst;
  for (int t = threadIdx.x; t < CRED; t += 256) av[t] = att[h * CRED + t];
  __syncthreads();
#pragma unroll
  for (int half = 0; half < 2; ++half) {
    const int c = threadIdx.x + half * 256;
    const float* wrow = w_gat + (size_t)c * KGAT + h * CRED;
    float acc = 0.f;
    for (int j = 0; j < CRED; j += 4) {
      const float4 w = *(const float4*)&wrow[j];
      acc += w.x * av[j] + w.y * av[j + 1] + w.z * av[j + 2] + w.w * av[j + 3];
    }
    P[(size_t)sh * CRED + c] = acc;
  }
}

// ---------- a_all[s][n][h] = xr[n] . P[s][h]   (one wave per node) ---------
__global__ __launch_bounds__(256) void att_kernel(
    const u16* __restrict__ xr, const float* __restrict__ P,
    float* __restrict__ a_all)
{
  const int wave = threadIdx.x >> 6, lane = threadIdx.x & 63;
  const int m = blockIdx.x * 4 + wave;
  const int sh = lane & 15, q = lane >> 4;
  const u16* xp = xr + (size_t)m * CRED + q * 128;
  const float* Pp = P + (size_t)sh * CRED + q * 128;
  float s = 0.f;
#pragma unroll
  for (int c = 0; c < 128; c += 8) {
    u16x8 xv = *(const u16x8*)&xp[c];
#pragma unroll
    for (int t = 0; t < 8; ++t) s += b2f(xv[t]) * Pp[c + t];
  }
  s += __shfl_xor(s, 16);
  s += __shfl_xor(s, 32);
  if (q == 0)
    a_all[(size_t)(sh >> 3) * MTOT * HEADS + (size_t)m * HEADS + (sh & 7)] = s;
}

// ---- per node: softmax alphas (8 heads x 5 edges) in LDS, then
//      gat[n][j] = bias[j] + sum_e sum_h (alpha[e][h]/8) * Y[v_e][h*512+j] ---
__global__ __launch_bounds__(256) void agg2_kernel(
    const u16* __restrict__ Y, const float* __restrict__ a_all,
    const float* __restrict__ gat_bias, u16* __restrict__ gat)
{
  int bid = blockIdx.x;
  bid = (bid & 7) * (MTOT >> 3) + (bid >> 3);
  const int u = bid & 255, b = bid >> 8;
  const int gi = u >> 4, gj = u & 15;
  const size_t nb = (size_t)b * NPIX;
  const int t = threadIdx.x;

  const int v0 = u;
  const int v1 = (gi > 0)  ? u - 16 : -1;
  const int v2 = (gi < 15) ? u + 16 : -1;
  const int v3 = (gj > 0)  ? u - 1  : -1;
  const int v4 = (gj < 15) ? u + 1  : -1;
  const int vs[5] = { v0, v1, v2, v3, v4 };

  __shared__ float alf[5][8];
  if (t < 8) {
    const int h = t;
    const float* a_src = a_all;
    const float* a_dst = a_all + (size_t)MTOT * HEADS;
    const float adst = a_dst[(nb + u) * HEADS + h];
    float l[5];
    float mx = -1e30f;
#pragma unroll
    for (int e = 0; e < 5; ++e) {
      if (vs[e] >= 0) {
        const float xx = a_src[(nb + vs[e]) * HEADS + h] + adst;
        l[e] = xx > 0.f ? xx : 0.2f * xx;
        mx = fmaxf(mx, l[e]);
      } else {
        l[e] = -1e30f;
      }
    }
    float s = 0.f, ee[5];
#pragma unroll
    for (int e = 0; e < 5; ++e) {
      ee[e] = (vs[e] >= 0) ? __expf(l[e] - mx) : 0.f;
      s += ee[e];
    }
    const float inv = 0.125f / s;
#pragma unroll
    for (int e = 0; e < 5; ++e) alf[e][h] = ee[e] * inv;
  }
  __syncthreads();

  const int j0 = t * 2;
  float o0 = gat_bias[j0], o1 = gat_bias[j0 + 1];
#pragma unroll
  for (int e = 0; e < 5; ++e) {
    const int vv = vs[e];
    if (vv < 0) continue;
    const u16* yp = Y + (nb + vv) * (size_t)KGAT + j0;
#pragma unroll
    for (int h = 0; h < HEADS; ++h) {
      const float a = alf[e][h];
      const unsigned w = *(const unsigned*)(yp + h * CRED);
      o0 += a * b2f((u16)(w & 0xffffu));
      o1 += a * b2f((u16)(w >> 16));
    }
  }
  const unsigned ow = ((unsigned)f2b(o1) << 16) | (unsigned)f2b(o0);
  *(unsigned*)&gat[(nb + u) * (size_t)CRED + j0] = ow;
}

// ---------------------------------------------------------------------------
extern "C" void kernel_launch(void* const* d_in, const int* in_sizes, int n_in,
                              void* d_out, int out_size, void* d_ws, size_t ws_size,
                              hipStream_t stream)
{
  const float* x         = (const float*)d_in[0];
  const float* w_reduce  = (const float*)d_in[1];
  const float* g_red     = (const float*)d_in[2];
  const float* b_red     = (const float*)d_in[3];
  const float* m_red     = (const float*)d_in[4];
  const float* v_red     = (const float*)d_in[5];
  const float* w_gat     = (const float*)d_in[6];
  const float* att_src   = (const float*)d_in[7];
  const float* att_dst   = (const float*)d_in[8];
  const float* gat_bias  = (const float*)d_in[9];
  const float* w_restore = (const float*)d_in[10];
  const float* g_res     = (const float*)d_in[11];
  const float* b_res     = (const float*)d_in[12];
  const float* m_res     = (const float*)d_in[13];
  const float* v_res     = (const float*)d_in[14];

  constexpr size_t SZ_Y    = (size_t)MTOT * KGAT * 2;
  constexpr size_t SZ_XR   = (size_t)MTOT * CRED * 2;
  constexpr size_t SZ_GAT  = SZ_XR;
  constexpr size_t SZ_WGT  = (size_t)KGAT * CRED * 2;
  constexpr size_t SZ_WRD  = (size_t)CRED * CIN * 2;
  constexpr size_t SZ_WRS  = (size_t)COUT * CRED * 2;
  constexpr size_t SZ_P    = (size_t)16 * CRED * 4;
  char* ws = (char*)d_ws;
  u16*   Y      = (u16*)ws;
  u16*   xt     = (u16*)ws;  // alias of Y
  u16*   xr     = (u16*)(ws + SZ_Y);
  u16*   gat    = (u16*)(ws + SZ_Y + SZ_XR);
  u16*   WgT2   = (u16*)(ws + SZ_Y + SZ_XR + SZ_GAT);
  u16*   wred_b = (u16*)(ws + SZ_Y + SZ_XR + SZ_GAT + SZ_WGT);
  u16*   wres_b = (u16*)(ws + SZ_Y + SZ_XR + SZ_GAT + SZ_WGT + SZ_WRD);
  float* P      = (float*)(ws + SZ_Y + SZ_XR + SZ_GAT + SZ_WGT + SZ_WRD + SZ_WRS);
  float* a_all  = (float*)(ws + SZ_Y + SZ_XR + SZ_GAT + SZ_WGT + SZ_WRD + SZ_WRS + SZ_P);
  float* outp   = (float*)d_out;

  // allow 128 KiB dynamic LDS for the pipelined GEMM (idempotent)
  hipFuncSetAttribute((const void*)gemm8p_kernel,
                      hipFuncAttributeMaxDynamicSharedMemorySize, 131072);

  trcvt_kernel<<<dim3(4, 16, 64), 256, 0, stream>>>(
      x, xt, NPIX, CIN, (long)CIN * NPIX, (long)CIN * NPIX);
  trcvt_kernel<<<dim3(64, 8, 1), 256, 0, stream>>>(
      w_gat, WgT2, KGAT, CRED, 0, 0);
  cvt_kernel<<<(CRED * CIN) / 2048, 256, 0, stream>>>(w_reduce, wred_b);
  cvt_kernel<<<(COUT * CRED) / 2048, 256, 0, stream>>>(w_restore, wres_b);
  gemm_kernel<1><<<dim3(4, 128), 256, 0, stream>>>(
      xt, wred_b, xr, nullptr, g_red, b_red, m_red, v_red, nullptr, CIN, CRED);
  attproj_kernel<<<16, 256, 0, stream>>>(w_gat, att_src, att_dst, P);
  att_kernel<<<MTOT / 4, 256, 0, stream>>>(xr, P, a_all);
  gemm8p_kernel<<<dim3(16, 64), 512, 131072, stream>>>(xr, WgT2, Y);
  agg2_kernel<<<MTOT, 256, 0, stream>>>(Y, a_all, gat_bias, gat);
  gemm_kernel<3><<<dim3(8, 128), 256, 0, stream>>>(
      gat, wres_b, nullptr, outp, g_res, b_res, m_res, v_res, x, CRED, COUT);
  (void)in_sizes; (void)n_in; (void)out_size; (void)ws_size;
}